// Round 15
// baseline (78.362 us; speedup 1.0000x reference)
//
#include <hip/hip_runtime.h>
#include <hip/hip_bf16.h>

typedef __bf16 bf16x8 __attribute__((ext_vector_type(8)));
typedef float f32x4 __attribute__((ext_vector_type(4)));
typedef ushort us8 __attribute__((ext_vector_type(8)));

#define MFMA(a, b, c) __builtin_amdgcn_mfma_f32_16x16x32_bf16((a), (b), (c), 0, 0, 0)

static constexpr int T_LEN = 2048;
static constexpr int C_DIM = 1024;
static constexpr int H_DIM = 128;
static constexpr int M_ROWS = 8 * 2048;    // 16384
static constexpr int N_COLS = 384;         // 3 * 128
static constexpr int SLOTS_PER_B = 528;    // partial slots (qi>=32)
static constexpr int PSTR = 72;            // P buffer row stride
static constexpr int KSTR = 136;           // K LDS row stride (272B, 2-way max)
static constexpr int VSTR = 72;            // V LDS row stride (144B, 2-way max)

__device__ __forceinline__ ushort f2bf(float f) {
  union { float f; unsigned u; } v; v.f = f;
  unsigned u = v.u;
  u += 0x7fffu + ((u >> 16) & 1u);
  return (ushort)(u >> 16);
}
__device__ __forceinline__ float bf2f(ushort u) {
  union { unsigned u; float f; } v; v.u = (unsigned)u << 16;
  return v.f;
}

// raw barrier: lgkmcnt(0) for LDS visibility, NO vmcnt drain.
__device__ __forceinline__ void waitbar() {
  asm volatile("s_waitcnt lgkmcnt(0)" ::: "memory");
  __builtin_amdgcn_s_barrier();
  __builtin_amdgcn_sched_barrier(0);
}

// paired-row swizzled LDS byte address for logical (row, 16B-slot):
//   byte = (row>>1)*128 + (row&1)*64 + ((slot*16) ^ (((row>>1)&3)<<4))
__device__ __forceinline__ int swz_byte(int row, int slot) {
  return (row >> 1) * 128 + (row & 1) * 64 + ((slot * 16) ^ (((row >> 1) & 3) << 4));
}

// ---------------------------------------------------------------------------
// Kernel 0: Wq/Wk/Wv fp32 [1024][128] -> bf16 wt_frag, MFMA-FRAGMENT layout:
//   wt[((kt*24 + cg)*64 + lane)*8 + j] = W(c = kt*32 + (lane>>4)*8 + j,
//                                          gc = cg*16 + (lane&15))
// A wave's B-fragment load for (kt, cg) is ONE contiguous 1 KB read.
// ---------------------------------------------------------------------------
__global__ void wt_convert(const float* __restrict__ Wq,
                           const float* __restrict__ Wk,
                           const float* __restrict__ Wv,
                           ushort* __restrict__ wt) {
  int o = blockIdx.x * 256 + threadIdx.x;   // 0..393215
  int kt = o / 12288;                        // 24 cg * 64 lanes * 8 elems
  int rem = o - kt * 12288;
  int cg = rem >> 9;
  int lane = (rem >> 3) & 63;
  int j = rem & 7;
  int gc = cg * 16 + (lane & 15);
  int c  = kt * 32 + (lane >> 4) * 8 + j;
  int mat = gc >> 7;
  int h   = gc & 127;
  const float* W = (mat == 0) ? Wq : ((mat == 1) ? Wk : Wv);
  wt[o] = f2bf(W[c * H_DIM + h]);
}

// ---------------------------------------------------------------------------
// Kernel 1: fused QKV projection v5.
//  - B operand: direct global fragment loads from wt_frag (L2-resident,
//    1 KB contiguous per load) — NO B LDS staging at all.
//  - A operand: LDS-staged (2x2 KB dbuf), paired-row swizzle, raw-barrier
//    ping-pong, prefetch distance 2 (round-14-proven).
//  - BM=32, BN=192 -> 1024 blocks (4/CU, 16 waves/CU). 6 MFMA/wave/iter.
// ---------------------------------------------------------------------------
__global__ __launch_bounds__(256, 4) void qkv_gemm(const float* __restrict__ X,
                                                   const ushort* __restrict__ wt,
                                                   ushort* __restrict__ qws,
                                                   ushort* __restrict__ kws,
                                                   ushort* __restrict__ vtws) {
  __shared__ ushort As[2][16 * 64];   // logical [32][32] paired -> 2 KB each
  const int tid = threadIdx.x;
  const int wid = tid >> 6, lane = tid & 63;
  const int lg = lane >> 4, lr = lane & 15;
  const int m0 = (blockIdx.x >> 1) * 32;
  const int n0 = (blockIdx.x & 1) * 192;
  const int cgb = (blockIdx.x & 1) * 12 + wid * 3;   // wave's first colgroup
  const float QSCL = 0.03125f * 1.44269504f;

  // A staging: ar = tid>>3 (0..31), ac = tid&7 -> float4 at col ac*4
  const int ar = tid >> 3, ac = tid & 7;
  const float* gA = &X[(size_t)(m0 + ar) * C_DIM + ac * 4];
  const int awb = swz_byte(ar, ac >> 1) + (ac & 1) * 8;

  // fragment read bases (row-step 16 -> +1024 B exactly)
  const int afb = swz_byte(lr, lg);

  f32x4 acc[2][3];
#pragma unroll
  for (int r = 0; r < 2; ++r)
#pragma unroll
    for (int c = 0; c < 3; ++c)
      acc[r][c] = f32x4{0.f, 0.f, 0.f, 0.f};

  float4 aE, aO;
  us8 bE0, bE1, bE2, bO0, bO1, bO2;

  // ---- prologue ----
  {
    float4 x0 = *(const float4*)gA;           // tile 0
    ushort4 av;
    av.x = f2bf(x0.x); av.y = f2bf(x0.y); av.z = f2bf(x0.z); av.w = f2bf(x0.w);
    *(ushort4*)((char*)&As[0][0] + awb) = av;
  }
  aE = *(const float4*)(gA + 32);             // tile 1
  aO = *(const float4*)(gA + 64);             // tile 2
  {
    const ushort* g0 = &wt[((size_t)(0 * 24 + cgb) * 64 + lane) * 8];
    bE0 = *(const us8*)(g0);
    bE1 = *(const us8*)(g0 + 512);            // +1 cg = 64 lanes * 8
    bE2 = *(const us8*)(g0 + 1024);
    const ushort* g1 = &wt[((size_t)(1 * 24 + cgb) * 64 + lane) * 8];
    bO0 = *(const us8*)(g1);
    bO1 = *(const us8*)(g1 + 512);
    bO2 = *(const us8*)(g1 + 1024);
  }
  waitbar();   // tile0 staged & visible

  for (int k2 = 0; k2 < 32; k2 += 2) {
    // ==== even iter kt=k2: write tile k2+1 (aE) -> As[1]; compute As[0]+bE;
    //      issue A(k2+3)->aE, B(k2+2)->bE ====
    {
      ushort4 av;
      av.x = f2bf(aE.x); av.y = f2bf(aE.y); av.z = f2bf(aE.z); av.w = f2bf(aE.w);
      *(ushort4*)((char*)&As[1][0] + awb) = av;
    }
    if (k2 + 3 < 32) aE = *(const float4*)(gA + (k2 + 3) * 32);
    {
      bf16x8 a0 = *(const bf16x8*)((const char*)&As[0][0] + afb);
      bf16x8 a1 = *(const bf16x8*)((const char*)&As[0][0] + afb + 1024);
      acc[0][0] = MFMA(a0, (bf16x8)bE0, acc[0][0]);
      acc[1][0] = MFMA(a1, (bf16x8)bE0, acc[1][0]);
      acc[0][1] = MFMA(a0, (bf16x8)bE1, acc[0][1]);
      acc[1][1] = MFMA(a1, (bf16x8)bE1, acc[1][1]);
      acc[0][2] = MFMA(a0, (bf16x8)bE2, acc[0][2]);
      acc[1][2] = MFMA(a1, (bf16x8)bE2, acc[1][2]);
    }
    if (k2 + 2 < 32) {
      const ushort* g = &wt[((size_t)((k2 + 2) * 24 + cgb) * 64 + lane) * 8];
      bE0 = *(const us8*)(g);
      bE1 = *(const us8*)(g + 512);
      bE2 = *(const us8*)(g + 1024);
    }
    waitbar();

    // ==== odd iter kt=k2+1: write tile k2+2 (aO) -> As[0]; compute As[1]+bO;
    //      issue A(k2+4)->aO, B(k2+3)->bO ====
    if (k2 + 2 < 32) {
      ushort4 av;
      av.x = f2bf(aO.x); av.y = f2bf(aO.y); av.z = f2bf(aO.z); av.w = f2bf(aO.w);
      *(ushort4*)((char*)&As[0][0] + awb) = av;
    }
    if (k2 + 4 < 32) aO = *(const float4*)(gA + (k2 + 4) * 32);
    {
      bf16x8 a0 = *(const bf16x8*)((const char*)&As[1][0] + afb);
      bf16x8 a1 = *(const bf16x8*)((const char*)&As[1][0] + afb + 1024);
      acc[0][0] = MFMA(a0, (bf16x8)bO0, acc[0][0]);
      acc[1][0] = MFMA(a1, (bf16x8)bO0, acc[1][0]);
      acc[0][1] = MFMA(a0, (bf16x8)bO1, acc[0][1]);
      acc[1][1] = MFMA(a1, (bf16x8)bO1, acc[1][1]);
      acc[0][2] = MFMA(a0, (bf16x8)bO2, acc[0][2]);
      acc[1][2] = MFMA(a1, (bf16x8)bO2, acc[1][2]);
    }
    if (k2 + 3 < 32) {
      const ushort* g = &wt[((size_t)((k2 + 3) * 24 + cgb) * 64 + lane) * 8];
      bO0 = *(const us8*)(g);
      bO1 = *(const us8*)(g + 512);
      bO2 = *(const us8*)(g + 1024);
    }
    waitbar();
  }

  // epilogue: C frag layout col=lane&15, row=(lane>>4)*4+j
#pragma unroll
  for (int c = 0; c < 3; ++c) {
    int gc = n0 + wid * 48 + c * 16 + lr;
    int mat = gc >> 7, h = gc & 127;
#pragma unroll
    for (int r = 0; r < 2; ++r) {
#pragma unroll
      for (int j = 0; j < 4; ++j) {
        int gr = m0 + r * 16 + lg * 4 + j;
        float val = acc[r][c][j];
        ushort ov = f2bf(mat == 0 ? val * QSCL : val);
        if (mat == 0) {
          qws[(size_t)gr * H_DIM + h] = ov;
        } else if (mat == 1) {
          kws[(size_t)gr * H_DIM + h] = ov;
        } else {
          int b = gr >> 11, t = gr & 2047;
          vtws[((size_t)b * H_DIM + h) * T_LEN + t] = ov;
        }
      }
    }
  }
}

// ---------------------------------------------------------------------------
// Kernel 2a: flash partial pass, block-cooperative LDS-staged K/V
// (unchanged from round 9).
// ---------------------------------------------------------------------------
__global__ __launch_bounds__(256, 3) void attn_part(const ushort* __restrict__ qws,
                                                    const ushort* __restrict__ kws,
                                                    const ushort* __restrict__ vtws,
                                                    float* __restrict__ pml,
                                                    ushort* __restrict__ pacc,
                                                    float* __restrict__ out) {
  __shared__ ushort Klds[64 * KSTR];
  __shared__ ushort Vlds[128 * VSTR];
  __shared__ ushort Pw[4][16 * PSTR];

  const int tid = threadIdx.x;
  const int wid = tid >> 6, lane = tid & 63;
  const int lg = lane >> 4, lr = lane & 15;
  const int bid = blockIdx.x;
  const int b = bid & 7;
  const int item = bid >> 3;

  int qb, ck;
  bool direct;
  if (item < 8) {
    qb = item; ck = 0; direct = true;
  } else {
    const int p = item - 8;
    direct = false;
    if (p < 12)      { int q = p / 3;        qb = 8 + q;  ck = p - q * 3; }
    else if (p < 28) { int q = (p - 12) >> 2; qb = 12 + q; ck = (p - 12) & 3; }
    else if (p < 48) { int q = (p - 28) / 5; qb = 16 + q; ck = (p - 28) - q * 5; }
    else if (p < 72) { int q = (p - 48) / 6; qb = 20 + q; ck = (p - 48) - q * 6; }
    else if (p < 100){ int q = (p - 72) / 7; qb = 24 + q; ck = (p - 72) - q * 7; }
    else             { int q = (p - 100) >> 3; qb = 28 + q; ck = (p - 100) & 7; }
  }
  const int qi = qb * 4 + wid;
  const int q0 = qi * 16;
  const int nt = qb + 1;
  const int kvt_lo = direct ? 0 : ck * 4;
  const int kvt_hi = direct ? nt : min(ck * 4 + 4, nt);
  const size_t tokbase = (size_t)b * T_LEN;
  const ushort* vb = vtws + (size_t)b * H_DIM * T_LEN;

  const int kr = tid >> 2, kseg = tid & 3;
  const int vr = tid >> 1, vseg = tid & 1;
  const ushort* gK = &kws[(tokbase + kr) * H_DIM + kseg * 32];
  const ushort* gV = &vb[(size_t)vr * T_LEN + vseg * 32];

  bf16x8 qf[4];
#pragma unroll
  for (int hk = 0; hk < 4; ++hk)
    qf[hk] = *(const bf16x8*)&qws[(tokbase + q0 + lr) * H_DIM + hk * 32 + lg * 8];

  f32x4 acc[8];
#pragma unroll
  for (int hf = 0; hf < 8; ++hf) acc[hf] = f32x4{0.f, 0.f, 0.f, 0.f};
  float mrun = -INFINITY, lrun = 0.f;

  ushort* Pme = &Pw[wid][0];

  us8 kreg[4], vreg[4];
#pragma unroll
  for (int i = 0; i < 4; ++i) {
    kreg[i] = *(const us8*)(gK + (size_t)kvt_lo * 64 * H_DIM + i * 8);
    vreg[i] = *(const us8*)(gV + kvt_lo * 64 + i * 8);
  }

  for (int kvt = kvt_lo; kvt < kvt_hi; ++kvt) {
    const int kv0 = kvt * 64;

    __syncthreads();
#pragma unroll
    for (int i = 0; i < 4; ++i) {
      *(us8*)&Klds[kr * KSTR + kseg * 32 + i * 8] = kreg[i];
      *(us8*)&Vlds[vr * VSTR + vseg * 32 + i * 8] = vreg[i];
    }
    if (kvt + 1 < kvt_hi) {
#pragma unroll
      for (int i = 0; i < 4; ++i) {
        kreg[i] = *(const us8*)(gK + (size_t)(kv0 + 64) * H_DIM + i * 8);
        vreg[i] = *(const us8*)(gV + kv0 + 64 + i * 8);
      }
    }
    __syncthreads();

    f32x4 s[4];
#pragma unroll
    for (int c = 0; c < 4; ++c) {
      f32x4 sc = f32x4{0.f, 0.f, 0.f, 0.f};
#pragma unroll
      for (int hk = 0; hk < 4; ++hk) {
        bf16x8 kf = *(const bf16x8*)&Klds[(c * 16 + lr) * KSTR + hk * 32 + lg * 8];
        sc = MFMA(kf, qf[hk], sc);
      }
      s[c] = sc;
    }

    if (kvt == nt - 1) {
#pragma unroll
      for (int c = 0; c < 4; ++c)
#pragma unroll
        for (int j = 0; j < 4; ++j) {
          int kv = kv0 + c * 16 + lg * 4 + j;
          if (kv > q0 + lr) s[c][j] = -INFINITY;
        }
    }

    float mx = s[0][0];
#pragma unroll
    for (int c = 0; c < 4; ++c)
#pragma unroll
      for (int j = 0; j < 4; ++j) mx = fmaxf(mx, s[c][j]);
    mx = fmaxf(mx, __shfl_xor(mx, 16));
    mx = fmaxf(mx, __shfl_xor(mx, 32));

    float mnew = fmaxf(mrun, mx);
    float scold = exp2f(mrun - mnew);

    float rsum = 0.f;
#pragma unroll
    for (int c = 0; c < 4; ++c)
#pragma unroll
      for (int j = 0; j < 4; ++j) {
        float p = exp2f(s[c][j] - mnew);
        s[c][j] = p;
        rsum += p;
      }

#pragma unroll
    for (int c = 0; c < 4; ++c) {
      ushort4 u;
      u.x = f2bf(s[c][0]); u.y = f2bf(s[c][1]);
      u.z = f2bf(s[c][2]); u.w = f2bf(s[c][3]);
      *(ushort4*)&Pme[lr * PSTR + c * 16 + lg * 4] = u;
    }

    bf16x8 v0[8];
#pragma unroll
    for (int hf = 0; hf < 8; ++hf)
      v0[hf] = *(const bf16x8*)&Vlds[(hf * 16 + lr) * VSTR + lg * 8];

    rsum += __shfl_xor(rsum, 16);
    rsum += __shfl_xor(rsum, 32);

    lrun = lrun * scold + rsum;
    mrun = mnew;
#pragma unroll
    for (int hf = 0; hf < 8; ++hf)
#pragma unroll
      for (int j = 0; j < 4; ++j) acc[hf][j] *= scold;

    bf16x8 pa0 = *(const bf16x8*)&Pme[lr * PSTR + lg * 8];
    bf16x8 pa1 = *(const bf16x8*)&Pme[lr * PSTR + 32 + lg * 8];

#pragma unroll
    for (int hf = 0; hf < 8; ++hf)
      acc[hf] = MFMA(v0[hf], pa0, acc[hf]);
#pragma unroll
    for (int hf = 0; hf < 8; ++hf) {
      bf16x8 v1 = *(const bf16x8*)&Vlds[(hf * 16 + lr) * VSTR + 32 + lg * 8];
      acc[hf] = MFMA(v1, pa1, acc[hf]);
    }
  }

  if (direct) {
    float inv = 1.0f / lrun;
    float* op = &out[(tokbase + q0 + lr) * H_DIM + lg * 4];
#pragma unroll
    for (int hf = 0; hf < 8; ++hf) {
      float4 r0 = make_float4(acc[hf][0] * inv, acc[hf][1] * inv,
                              acc[hf][2] * inv, acc[hf][3] * inv);
      *(float4*)(op + hf * 16) = r0;
    }
  } else {
    int base;
    if (qi < 48)       base = (qi - 32) * 3;
    else if (qi < 64)  base = 48 + (qi - 48) * 4;
    else if (qi < 80)  base = 112 + (qi - 64) * 5;
    else if (qi < 96)  base = 192 + (qi - 80) * 6;
    else if (qi < 112) base = 288 + (qi - 96) * 7;
    else               base = 400 + (qi - 112) * 8;
    const size_t slot = (size_t)b * SLOTS_PER_B + base + ck;
    if (lg == 0) {
      pml[slot * 32 + lr] = mrun;
      pml[slot * 32 + 16 + lr] = lrun;
    }
    ushort* ap = &pacc[slot * 2048 + (size_t)lr * 128 + lg * 4];
#pragma unroll
    for (int hf = 0; hf < 8; ++hf) {
      ushort4 u;
      u.x = f2bf(acc[hf][0]); u.y = f2bf(acc[hf][1]);
      u.z = f2bf(acc[hf][2]); u.w = f2bf(acc[hf][3]);
      *(ushort4*)(ap + hf * 16) = u;
    }
  }
}

// ---------------------------------------------------------------------------
// Kernel 2b: online merge of 3..8 partials per (b, qi) for qi >= 32.
// (unchanged)
// ---------------------------------------------------------------------------
__global__ __launch_bounds__(256) void attn_merge(const float* __restrict__ pml,
                                                  const ushort* __restrict__ pacc,
                                                  float* __restrict__ out) {
  const int bid = blockIdx.x;
  const int b = bid & 7, qi = (bid >> 3) + 32;
  int base, nch;
  if (qi < 48)       { base = (qi - 32) * 3;        nch = 3; }
  else if (qi < 64)  { base = 48 + (qi - 48) * 4;   nch = 4; }
  else if (qi < 80)  { base = 112 + (qi - 64) * 5;  nch = 5; }
  else if (qi < 96)  { base = 192 + (qi - 80) * 6;  nch = 6; }
  else if (qi < 112) { base = 288 + (qi - 96) * 7;  nch = 7; }
  else               { base = 400 + (qi - 112) * 8; nch = 8; }
  const size_t slot0 = (size_t)b * SLOTS_PER_B + base;
  const int tid = threadIdx.x;
  const int r = tid >> 4, c0 = (tid & 15) * 8;

  float mrun = -INFINITY, L = 0.f;
  float o[8];
#pragma unroll
  for (int i = 0; i < 8; ++i) o[i] = 0.f;

  for (int ck = 0; ck < nch; ++ck) {
    const size_t s = slot0 + ck;
    float m = pml[s * 32 + r];
    float l = pml[s * 32 + 16 + r];
    float mn = fmaxf(mrun, m);
    float sc = exp2f(mrun - mn);
    float w  = exp2f(m - mn);
    L = L * sc + w * l;
    const ushort* ap = &pacc[s * 2048 + (size_t)r * 128 + c0];
    ushort4 u0 = *(const ushort4*)ap;
    ushort4 u1 = *(const ushort4*)(ap + 4);
    o[0] = o[0] * sc + w * bf2f(u0.x); o[1] = o[1] * sc + w * bf2f(u0.y);
    o[2] = o[2] * sc + w * bf2f(u0.z); o[3] = o[3] * sc + w * bf2f(u0.w);
    o[4] = o[4] * sc + w * bf2f(u1.x); o[5] = o[5] * sc + w * bf2f(u1.y);
    o[6] = o[6] * sc + w * bf2f(u1.z); o[7] = o[7] * sc + w * bf2f(u1.w);
    mrun = mn;
  }
  float invL = 1.0f / L;
  float4 r0 = make_float4(o[0] * invL, o[1] * invL, o[2] * invL, o[3] * invL);
  float4 r1 = make_float4(o[4] * invL, o[5] * invL, o[6] * invL, o[7] * invL);
  float* op = &out[((size_t)b * T_LEN + qi * 16 + r) * H_DIM + c0];
  *(float4*)op = r0;
  *(float4*)(op + 4) = r1;
}

// ---------------------------------------------------------------------------
// ws layout identical to rounds 8-14 (total 30,670,848 B, proven fit):
//   [0, 786432) wt_frag (dead after qkv_gemm; pml overlaps, 540,672 B)
//   qws / kws / vtws ; pacc = 8*528 slots * 2048 bf16
// ---------------------------------------------------------------------------
extern "C" void kernel_launch(void* const* d_in, const int* in_sizes, int n_in,
                              void* d_out, int out_size, void* d_ws, size_t ws_size,
                              hipStream_t stream) {
  const float* emb = (const float*)d_in[0];
  const float* Wq  = (const float*)d_in[1];
  const float* Wk  = (const float*)d_in[2];
  const float* Wv  = (const float*)d_in[3];
  float* out = (float*)d_out;

  ushort* wt   = (ushort*)d_ws;
  ushort* qws  = wt  + (size_t)N_COLS * C_DIM;
  ushort* kws  = qws + (size_t)M_ROWS * H_DIM;
  ushort* vtws = kws + (size_t)M_ROWS * H_DIM;
  ushort* pacc = vtws + (size_t)8 * H_DIM * T_LEN;
  float*  pml  = (float*)d_ws;   // overlaps dead wt region

  wt_convert<<<(N_COLS * C_DIM) / 256, 256, 0, stream>>>(Wq, Wk, Wv, wt);
  qkv_gemm<<<(M_ROWS / 32) * 2, 256, 0, stream>>>(emb, wt, qws, kws, vtws);
  attn_part<<<8 * 140, 256, 0, stream>>>(qws, kws, vtws, pml, pacc, out);
  attn_merge<<<8 * 96, 256, 0, stream>>>(pml, pacc, out);
}